// Round 10
// baseline (505.971 us; speedup 1.0000x reference)
//
#include <hip/hip_runtime.h>
#include <hip/hip_fp16.h>

#define N_NODES 100000
#define N_EDGES 1600000
#define N_GRAPHS 512
#define FEAT 128
#define EMB 32
#define ZROW N_NODES                        // dedicated zero row in hs/y tables
#define NCOPY 64                            // privatized pool accumulator copies
#define NBKT 500                            // dst buckets
#define NPB 200                             // nodes per bucket
#define COLCAP 5120                         // col slots per bucket (cnt + 7*NPB pad max ~4900)
#define ABLK 512                            // scatter blocks
#define EPB 3125                            // edges per scatter block (512*3125 = 1.6M exact)
#define CW (NBKT + 1)                       // coff row width (501)
#define EBCAP 3840                          // k_build LDS staging (bucket max ~3400, 7-sigma)
#define NTILE (N_NODES / 16)                // 6250 MFMA row tiles
#define AGB 3125                            // agg blocks (32 nodes/block: 4 waves x 8 nodes)

typedef unsigned short u16;
typedef unsigned int u32;
typedef _Float16 f16;
typedef float f32x4 __attribute__((ext_vector_type(4)));
typedef unsigned short u16x4 __attribute__((ext_vector_type(4)));
typedef f16 f16x8 __attribute__((ext_vector_type(8)));

__device__ __forceinline__ u16x4 f4_to_h4(float4 f) {
  union { unsigned int u; __half2 h; } a, b;
  a.h = __float22half2_rn(make_float2(f.x, f.y));
  b.h = __float22half2_rn(make_float2(f.z, f.w));
  u16x4 r;
  r.x = (u16)(a.u & 0xffff); r.y = (u16)(a.u >> 16);
  r.z = (u16)(b.u & 0xffff); r.w = (u16)(b.u >> 16);
  return r;
}

__device__ __forceinline__ float4 relu_row(float4 acc, float d, float4 bq) {
  float4 o;
  o.x = fmaxf(fmaf(acc.x, d, bq.x), 0.f);
  o.y = fmaxf(fmaf(acc.y, d, bq.y), 0.f);
  o.z = fmaxf(fmaf(acc.z, d, bq.z), 0.f);
  o.w = fmaxf(fmaf(acc.w, d, bq.w), 0.f);
  return o;
}

// ---------------- k_scat: fully-coalesced block-local counting sort ----------------
// R8-proven. R10: also zeroes gaccP + done counter (memset dispatch deleted).

__global__ __launch_bounds__(256) void k_scat(const int* __restrict__ src,
                                              const int* __restrict__ dst,
                                              int* __restrict__ coff,
                                              u32* __restrict__ binbuf,
                                              float* __restrict__ gaccP,
                                              int* __restrict__ done) {
  __shared__ int h[NBKT];
  __shared__ int loff[NBKT + 1];
  __shared__ int curs[NBKT];
  __shared__ int sc[256];
  __shared__ u32 ebuf[EPB];
  int k = blockIdx.x, t = threadIdx.x;
  // zero the pool accumulators (NCOPY*N_GRAPHS = 32768 floats; 64 per block)
  if (t < 64) gaccP[k * 64 + t] = 0.f;
  if (k == 0 && t == 0) *done = 0;
  for (int i = t; i < NBKT; i += 256) h[i] = 0;
  __syncthreads();
  int e0 = k * EPB;
#pragma unroll 4
  for (int e = e0 + t; e < e0 + EPB; e += 256)
    atomicAdd(&h[(u32)dst[e] / (u32)NPB], 1);
  __syncthreads();
  // exclusive scan over 500 bucket counts (2 per thread)
  int i0 = 2 * t, i1 = 2 * t + 1;
  int v0 = (i0 < NBKT) ? h[i0] : 0;
  int v1 = (i1 < NBKT) ? h[i1] : 0;
  int tsum = v0 + v1;
  sc[t] = tsum;
  __syncthreads();
  for (int o = 1; o < 256; o <<= 1) {
    int add = (t >= o) ? sc[t - o] : 0;
    __syncthreads();
    sc[t] += add;
    __syncthreads();
  }
  int p = sc[t] - tsum;
  if (i0 < NBKT) { loff[i0] = p; curs[i0] = p; }
  if (i1 < NBKT) { loff[i1] = p + v0; curs[i1] = p + v0; }
  if (t == 255) loff[NBKT] = sc[255];       // = EPB
  __syncthreads();
  // write offset row (coalesced, 501 ints)
  for (int i = t; i <= NBKT; i += 256) coff[k * CW + i] = loff[i];
  // stage edges bucket-sorted into LDS
#pragma unroll 4
  for (int e = e0 + t; e < e0 + EPB; e += 256) {
    u32 d = (u32)dst[e];
    int b = d / (u32)NPB;
    int r = atomicAdd(&curs[b], 1);
    ebuf[r] = (u32)src[e] * (u32)NPB + (d - (u32)b * NPB);
  }
  __syncthreads();
  // stream out contiguously (coalesced)
  u32* ob = binbuf + (size_t)k * EPB;
#pragma unroll 4
  for (int i = t; i < EPB; i += 256) ob[i] = ebuf[i];
}

// ---------------- k_build: per-bucket CSR from 512 runs, all-LDS pipeline ----------------

__global__ __launch_bounds__(256) void k_build(const u32* __restrict__ binbuf,
                                               const int* __restrict__ coff,
                                               int* __restrict__ col,
                                               int2* __restrict__ rowinfo,
                                               float* __restrict__ dis,
                                               u16* __restrict__ hs1,
                                               u16* __restrict__ y1) {
  __shared__ u32 ebuf[EBCAP];  // bucket's edges, gathered from the 512 runs
  __shared__ int c[NPB];       // histogram, then scatter cursor
  __shared__ int sc[256];      // scan workspace
  __shared__ int rpl[NPB];     // exclusive scan of pad8(deg)
  __shared__ int tot;
  int b = blockIdx.x, t = threadIdx.x;
  if (t == 0) tot = 0;
  for (int i = t; i < NPB; i += 256) c[i] = 0;
  __syncthreads();
  // gather this bucket's runs from every scatter block
  for (int k = t; k < ABLK; k += 256) {
    int s0 = coff[k * CW + b];
    int s1 = coff[k * CW + b + 1];
    int len = s1 - s0;
    if (len > 0) {
      int r = atomicAdd(&tot, len);
      const u32* p = binbuf + (size_t)k * EPB + s0;
      for (int j = 0; j < len; j++) ebuf[r + j] = p[j];
    }
  }
  __syncthreads();
  int cnt = tot;
  // node histogram
  for (int i = t; i < cnt; i += 256) {
    u32 p = ebuf[i];
    u32 s = p / (u32)NPB;
    atomicAdd(&c[p - s * (u32)NPB], 1);
  }
  __syncthreads();
  int deg = (t < NPB) ? c[t] : 0;
  int p8 = (deg + 7) & ~7;
  sc[t] = p8;
  __syncthreads();
  for (int o = 1; o < 256; o <<= 1) {
    int add = (t >= o) ? sc[t - o] : 0;
    __syncthreads();
    sc[t] += add;
    __syncthreads();
  }
  int colbase = b * COLCAP;
  if (t < NPB) {
    int rp = sc[t] - p8;
    rpl[t] = rp;
    int node = b * NPB + t;
    rowinfo[node] = make_int2(colbase + rp, p8);
    dis[node] = rsqrtf((float)deg + 1.0f);
    for (int j = deg; j < p8; j++) col[colbase + rp + j] = ZROW;  // pad slots
    c[t] = 0;                                                     // reset as cursor
  }
  __syncthreads();
  // scatter col (bucket-local region, L2-resident)
  for (int i = t; i < cnt; i += 256) {
    u32 p = ebuf[i];
    u32 s = p / (u32)NPB;
    int ld = (int)(p - s * (u32)NPB);
    int pos = atomicAdd(&c[ld], 1);
    col[colbase + rpl[ld] + pos] = (int)s;
  }
  if (b == 0)
    for (int i = t; i < EMB; i += 256) {
      hs1[(size_t)ZROW * EMB + i] = 0;      // zero rows for pad gathers
      y1[(size_t)ZROW * EMB + i] = 0;
    }
}

// ---------------- GEMM1 via MFMA 16x16x32 f16 (W in register B-frags) ----------------

__global__ __launch_bounds__(256) void k_gemm1(const float* __restrict__ x,
                                               const float* __restrict__ W1,
                                               const float* __restrict__ dis,
                                               u16* __restrict__ hs1) {
  int wid = (blockIdx.x * 256 + threadIdx.x) >> 6;   // wave id = 16-row tile
  if (wid >= NTILE) return;
  int l = threadIdx.x & 63;
  int m = l & 15, q = l >> 4;
  f16x8 B[4][2];
#pragma unroll
  for (int s = 0; s < 4; ++s)
#pragma unroll
    for (int h = 0; h < 2; ++h)
#pragma unroll
      for (int j = 0; j < 8; ++j)
        B[s][h][j] = (f16)W1[(s * 32 + q * 8 + j) * EMB + h * 16 + m];
  int row = wid * 16 + m;
  const float* xr = x + (size_t)row * FEAT + q * 8;
  f32x4 acc0 = {0.f, 0.f, 0.f, 0.f}, acc1 = {0.f, 0.f, 0.f, 0.f};
#pragma unroll
  for (int s = 0; s < 4; ++s) {
    f32x4 xa = __builtin_nontemporal_load((const f32x4*)(xr + s * 32));
    f32x4 xb = __builtin_nontemporal_load((const f32x4*)(xr + s * 32 + 4));
    f16x8 A;
    A[0] = (f16)xa.x; A[1] = (f16)xa.y; A[2] = (f16)xa.z; A[3] = (f16)xa.w;
    A[4] = (f16)xb.x; A[5] = (f16)xb.y; A[6] = (f16)xb.z; A[7] = (f16)xb.w;
    acc0 = __builtin_amdgcn_mfma_f32_16x16x32_f16(A, B[s][0], acc0, 0, 0, 0);
    acc1 = __builtin_amdgcn_mfma_f32_16x16x32_f16(A, B[s][1], acc1, 0, 0, 0);
  }
  f32x4 dq = *(const f32x4*)(dis + wid * 16 + q * 4);
  u16* o = hs1 + (size_t)(wid * 16) * EMB;
#pragma unroll
  for (int i = 0; i < 4; ++i) {
    int r = q * 4 + i;
    float dv = (i == 0) ? dq.x : (i == 1) ? dq.y : (i == 2) ? dq.z : dq.w;
    o[(size_t)r * EMB + m]      = __half_as_ushort(__float2half_rn(acc0[i] * dv));
    o[(size_t)r * EMB + 16 + m] = __half_as_ushort(__float2half_rn(acc1[i] * dv));
  }
}

// ---------------- Aggregation: 8 lanes/node, half2-native (R9-proven structural best) ----------------

__device__ __forceinline__ void acch(f32x4& A, uint2 v) {
  float2 f0 = __half22float2(*(__half2*)&v.x);
  float2 f1 = __half22float2(*(__half2*)&v.y);
  f32x4 f = {f0.x, f0.y, f1.x, f1.y};
  A += f;
}

__device__ __forceinline__ float4 agg_node(const u16* __restrict__ hs,
                                           const int2* __restrict__ rowinfo,
                                           const int* __restrict__ col,
                                           int node, int sub) {
  const uint2* t2 = (const uint2*)hs;       // row = 8 chunks of 8B
  int2 ri = rowinfo[node];
  int a0 = ri.x, na = ri.y;                 // pad8 degree; a0 8-slot aligned
  const int* cp = col + a0;
  f32x4 A = {0.f, 0.f, 0.f, 0.f};
  if (na > 0) {
    int4 c0 = *(const int4*)cp;
    int4 c1 = *(const int4*)(cp + 4);
    uint2 v0 = t2[(size_t)c0.x * 8 + sub];
    uint2 v1 = t2[(size_t)c0.y * 8 + sub];
    uint2 v2 = t2[(size_t)c0.z * 8 + sub];
    uint2 v3 = t2[(size_t)c0.w * 8 + sub];
    uint2 v4 = t2[(size_t)c1.x * 8 + sub];
    uint2 v5 = t2[(size_t)c1.y * 8 + sub];
    uint2 v6 = t2[(size_t)c1.z * 8 + sub];
    uint2 v7 = t2[(size_t)c1.w * 8 + sub];
    for (int i = 8; i < na; i += 8) {
      int4 d0 = *(const int4*)(cp + i);
      int4 d1 = *(const int4*)(cp + i + 4);
      uint2 w0 = t2[(size_t)d0.x * 8 + sub];  // next set in flight before consuming
      uint2 w1 = t2[(size_t)d0.y * 8 + sub];
      uint2 w2 = t2[(size_t)d0.z * 8 + sub];
      uint2 w3 = t2[(size_t)d0.w * 8 + sub];
      uint2 w4 = t2[(size_t)d1.x * 8 + sub];
      uint2 w5 = t2[(size_t)d1.y * 8 + sub];
      uint2 w6 = t2[(size_t)d1.z * 8 + sub];
      uint2 w7 = t2[(size_t)d1.w * 8 + sub];
      acch(A, v0); acch(A, v1); acch(A, v2); acch(A, v3);
      acch(A, v4); acch(A, v5); acch(A, v6); acch(A, v7);
      v0 = w0; v1 = w1; v2 = w2; v3 = w3;
      v4 = w4; v5 = w5; v6 = w6; v7 = w7;
    }
    acch(A, v0); acch(A, v1); acch(A, v2); acch(A, v3);
    acch(A, v4); acch(A, v5); acch(A, v6); acch(A, v7);
  }
  // self-loop contribution (row carries the src-side dis factor already)
  acch(A, t2[(size_t)node * 8 + sub]);
  return make_float4(A.x, A.y, A.z, A.w);
}

// grid = AGB blocks; wave handles 8 nodes, lane group (l>>3) one node, sub=l&7
__global__ __launch_bounds__(256) void k_agg1(const u16* __restrict__ hs,
                                              const int2* __restrict__ rowinfo,
                                              const int* __restrict__ col,
                                              const float* __restrict__ dis,
                                              const float* __restrict__ b,
                                              u16* __restrict__ out) {
  int t = threadIdx.x;
  int l = t & 63;
  int node = blockIdx.x * 32 + (t >> 6) * 8 + (l >> 3);
  int sub = l & 7;
  float4 A = agg_node(hs, rowinfo, col, node, sub);
  float d = dis[node];
  float4 bq = ((const float4*)b)[sub];
  float4 o = relu_row(A, d, bq);             // out1 = relu(A*d + b1)
  o.x *= d; o.y *= d; o.z *= d; o.w *= d;    // store y = out1 * dis (layer-2 src prescale)
  ((u16x4*)(out + (size_t)node * EMB))[sub] = f4_to_h4(o);
}

// R10: k_finalize folded in via threadfence + done-counter (last block finalizes).
__global__ __launch_bounds__(256) void k_agg2pool(const u16* __restrict__ hs,
                                                  const int2* __restrict__ rowinfo,
                                                  const int* __restrict__ col,
                                                  const float* __restrict__ dis,
                                                  const float* __restrict__ W2,
                                                  const float* __restrict__ b2,
                                                  const float* __restrict__ Wo,
                                                  const int* __restrict__ batch,
                                                  float* __restrict__ gaccP,
                                                  int* __restrict__ done,
                                                  const float* __restrict__ bo,
                                                  float* __restrict__ out) {
  __shared__ float W2L[32][32];              // W2[k][j], row-major
  __shared__ bool last;
  int t = threadIdx.x;
  for (int i = t; i < 32 * 32; i += 256) ((float*)W2L)[i] = W2[i];
  __syncthreads();
  int l = t & 63;
  int node = blockIdx.x * 32 + (t >> 6) * 8 + (l >> 3);
  int sub = l & 7;
  float4 A = agg_node(hs, rowinfo, col, node, sub);  // s = Sum(y[src]) + y[node]
  // z[4sub..4sub+3] = (s @ W2)[those cols]; s distributed across the node's 8 lanes
  int base = l & ~7;
  float4 z = make_float4(0.f, 0.f, 0.f, 0.f);
#pragma unroll
  for (int s8 = 0; s8 < 8; ++s8) {
    float sx = __shfl(A.x, base + s8);
    float sy = __shfl(A.y, base + s8);
    float sz = __shfl(A.z, base + s8);
    float sw = __shfl(A.w, base + s8);
    float4 w0 = *(const float4*)&W2L[4 * s8 + 0][sub * 4];
    float4 w1 = *(const float4*)&W2L[4 * s8 + 1][sub * 4];
    float4 w2 = *(const float4*)&W2L[4 * s8 + 2][sub * 4];
    float4 w3 = *(const float4*)&W2L[4 * s8 + 3][sub * 4];
    z.x = fmaf(sx, w0.x, fmaf(sy, w1.x, fmaf(sz, w2.x, fmaf(sw, w3.x, z.x))));
    z.y = fmaf(sx, w0.y, fmaf(sy, w1.y, fmaf(sz, w2.y, fmaf(sw, w3.y, z.y))));
    z.z = fmaf(sx, w0.z, fmaf(sy, w1.z, fmaf(sz, w2.z, fmaf(sw, w3.z, z.z))));
    z.w = fmaf(sx, w0.w, fmaf(sy, w1.w, fmaf(sz, w2.w, fmaf(sw, w3.w, z.w))));
  }
  float d = dis[node];
  float4 bq = ((const float4*)b2)[sub];
  float4 o = relu_row(z, d, bq);             // relu((s@W2)*dis + b2)
  float4 wq = ((const float4*)Wo)[sub];
  float p = o.x * wq.x + o.y * wq.y + o.z * wq.z + o.w * wq.w;
  p += __shfl_xor(p, 1);
  p += __shfl_xor(p, 2);
  p += __shfl_xor(p, 4);
  if (sub == 0)
    atomicAdd(&gaccP[(node & (NCOPY - 1)) * N_GRAPHS + batch[node]], p);
  // ---- last-block finalize ----
  __threadfence();                           // each thread orders its pool atomic
  __syncthreads();
  if (t == 0) last = (atomicAdd(done, 1) == AGB - 1);
  __syncthreads();
  if (last) {
    for (int g = t; g < N_GRAPHS; g += 256) {
      int lo = 0, hi = N_NODES;
      while (lo < hi) { int mid = (lo + hi) >> 1; if (batch[mid] < g) lo = mid + 1; else hi = mid; }
      int lo1 = lo; hi = N_NODES;
      while (lo < hi) { int mid = (lo + hi) >> 1; if (batch[mid] < g + 1) lo = mid + 1; else hi = mid; }
      int cntg = lo - lo1;
      float s = 0.f;
#pragma unroll 8
      for (int c = 0; c < NCOPY; ++c) s += gaccP[c * N_GRAPHS + g];
      out[g] = s / fmaxf((float)cntg, 1.0f) + bo[0];
    }
  }
}

// ---------------- launch ----------------

extern "C" void kernel_launch(void* const* d_in, const int* in_sizes, int n_in,
                              void* d_out, int out_size, void* d_ws, size_t ws_size,
                              hipStream_t stream) {
  const float* x     = (const float*)d_in[0];
  const int*   ei    = (const int*)d_in[1];   // [2, E]: src then dst
  const int*   batch = (const int*)d_in[2];
  const float* W1    = (const float*)d_in[3];
  const float* b1    = (const float*)d_in[4];
  const float* W2    = (const float*)d_in[5];
  const float* b2    = (const float*)d_in[6];
  const float* Wo    = (const float*)d_in[7];
  const float* bo    = (const float*)d_in[8];
  float* out = (float*)d_out;

  const int* src = ei;
  const int* dst = ei + N_EDGES;

  char* w = (char*)d_ws;
  float* gaccP   = (float*)w;  w += (size_t)NCOPY * N_GRAPHS * 4;     // zeroed by k_scat
  int*   done    = (int*)w;    w += 64;                               // zeroed by k_scat
  int*   coff    = (int*)w;    w += (size_t)ABLK * CW * 4;            // 1.03 MB
  u32*   binbuf  = (u32*)w;    w += (size_t)ABLK * EPB * 4;           // 6.4 MB
  int*   col     = (int*)w;    w += ((size_t)NBKT * COLCAP + 64) * 4; // 10.2 MB
  int2*  rowinfo = (int2*)w;   w += (size_t)(N_NODES + 8) * 8;        // 800 KB
  float* dis     = (float*)w;  w += (size_t)N_NODES * 4;
  u16*   hs1     = (u16*)w;    w += (size_t)(N_NODES + 1) * EMB * 2;  // +1 zero row
  u16*   out1    = (u16*)w;    w += (size_t)(N_NODES + 1) * EMB * 2;  // +1 zero row (y table)

  const int GB = (NTILE * 64 + 255) / 256;  // 1563 MFMA blocks

  k_scat<<<ABLK, 256, 0, stream>>>(src, dst, coff, binbuf, gaccP, done);
  k_build<<<NBKT, 256, 0, stream>>>(binbuf, coff, col, rowinfo, dis, hs1, out1);
  k_gemm1<<<GB, 256, 0, stream>>>(x, W1, dis, hs1);
  k_agg1<<<AGB, 256, 0, stream>>>(hs1, rowinfo, col, dis, b1, out1);
  k_agg2pool<<<AGB, 256, 0, stream>>>(out1, rowinfo, col, dis, W2, b2, Wo, batch,
                                      gaccP, done, bo, out);
}

// Round 11
// 210.625 us; speedup vs baseline: 2.4022x; 2.4022x over previous
//
#include <hip/hip_runtime.h>
#include <hip/hip_fp16.h>

#define N_NODES 100000
#define N_EDGES 1600000
#define N_GRAPHS 512
#define FEAT 128
#define EMB 32
#define ZROW N_NODES                        // dedicated zero row in hs/y tables
#define NCOPY 64                            // privatized pool accumulator copies
#define NBKT 500                            // dst buckets
#define NPB 200                             // nodes per bucket
#define COLCAP 5120                         // col slots per bucket (cnt + 7*NPB pad max ~4900)
#define ABLK 512                            // scatter blocks
#define EPB 3125                            // edges per scatter block (512*3125 = 1.6M exact)
#define CW (NBKT + 1)                       // coff row width (501)
#define EBCAP 3840                          // k_build LDS staging (bucket max ~3400, 7-sigma)
#define NTILE (N_NODES / 16)                // 6250 MFMA row tiles
#define AGB 3125                            // agg blocks (32 nodes/block: 4 waves x 8 nodes)

typedef unsigned short u16;
typedef unsigned int u32;
typedef _Float16 f16;
typedef float f32x4 __attribute__((ext_vector_type(4)));
typedef unsigned short u16x4 __attribute__((ext_vector_type(4)));
typedef f16 f16x8 __attribute__((ext_vector_type(8)));

__device__ __forceinline__ u16x4 f4_to_h4(float4 f) {
  union { unsigned int u; __half2 h; } a, b;
  a.h = __float22half2_rn(make_float2(f.x, f.y));
  b.h = __float22half2_rn(make_float2(f.z, f.w));
  u16x4 r;
  r.x = (u16)(a.u & 0xffff); r.y = (u16)(a.u >> 16);
  r.z = (u16)(b.u & 0xffff); r.w = (u16)(b.u >> 16);
  return r;
}

__device__ __forceinline__ float4 relu_row(float4 acc, float d, float4 bq) {
  float4 o;
  o.x = fmaxf(fmaf(acc.x, d, bq.x), 0.f);
  o.y = fmaxf(fmaf(acc.y, d, bq.y), 0.f);
  o.z = fmaxf(fmaf(acc.z, d, bq.z), 0.f);
  o.w = fmaxf(fmaf(acc.w, d, bq.w), 0.f);
  return o;
}

// ---------------- k_scat: fully-coalesced block-local counting sort ----------------
// R8-proven. Zeroes gaccP (kernel-boundary ordering -> no fence needed; memset deleted).
// R10 LESSON: do NOT put __threadfence() in a hot kernel -- device-scope fence on
// CDNA4 = L2 writeback/invalidate across XCDs; it destroyed agg2pool (26->330us).

__global__ __launch_bounds__(256) void k_scat(const int* __restrict__ src,
                                              const int* __restrict__ dst,
                                              int* __restrict__ coff,
                                              u32* __restrict__ binbuf,
                                              float* __restrict__ gaccP) {
  __shared__ int h[NBKT];
  __shared__ int loff[NBKT + 1];
  __shared__ int curs[NBKT];
  __shared__ int sc[256];
  __shared__ u32 ebuf[EPB];
  int k = blockIdx.x, t = threadIdx.x;
  // zero the pool accumulators (NCOPY*N_GRAPHS = 32768 floats; 64 per block)
  if (t < 64) gaccP[k * 64 + t] = 0.f;
  for (int i = t; i < NBKT; i += 256) h[i] = 0;
  __syncthreads();
  int e0 = k * EPB;
#pragma unroll 4
  for (int e = e0 + t; e < e0 + EPB; e += 256)
    atomicAdd(&h[(u32)dst[e] / (u32)NPB], 1);
  __syncthreads();
  // exclusive scan over 500 bucket counts (2 per thread)
  int i0 = 2 * t, i1 = 2 * t + 1;
  int v0 = (i0 < NBKT) ? h[i0] : 0;
  int v1 = (i1 < NBKT) ? h[i1] : 0;
  int tsum = v0 + v1;
  sc[t] = tsum;
  __syncthreads();
  for (int o = 1; o < 256; o <<= 1) {
    int add = (t >= o) ? sc[t - o] : 0;
    __syncthreads();
    sc[t] += add;
    __syncthreads();
  }
  int p = sc[t] - tsum;
  if (i0 < NBKT) { loff[i0] = p; curs[i0] = p; }
  if (i1 < NBKT) { loff[i1] = p + v0; curs[i1] = p + v0; }
  if (t == 255) loff[NBKT] = sc[255];       // = EPB
  __syncthreads();
  // write offset row (coalesced, 501 ints)
  for (int i = t; i <= NBKT; i += 256) coff[k * CW + i] = loff[i];
  // stage edges bucket-sorted into LDS
#pragma unroll 4
  for (int e = e0 + t; e < e0 + EPB; e += 256) {
    u32 d = (u32)dst[e];
    int b = d / (u32)NPB;
    int r = atomicAdd(&curs[b], 1);
    ebuf[r] = (u32)src[e] * (u32)NPB + (d - (u32)b * NPB);
  }
  __syncthreads();
  // stream out contiguously (coalesced)
  u32* ob = binbuf + (size_t)k * EPB;
#pragma unroll 4
  for (int i = t; i < EPB; i += 256) ob[i] = ebuf[i];
}

// ---------------- k_build: per-bucket CSR from 512 runs, all-LDS pipeline ----------------

__global__ __launch_bounds__(256) void k_build(const u32* __restrict__ binbuf,
                                               const int* __restrict__ coff,
                                               int* __restrict__ col,
                                               int2* __restrict__ rowinfo,
                                               float* __restrict__ dis,
                                               u16* __restrict__ hs1,
                                               u16* __restrict__ y1) {
  __shared__ u32 ebuf[EBCAP];  // bucket's edges, gathered from the 512 runs
  __shared__ int c[NPB];       // histogram, then scatter cursor
  __shared__ int sc[256];      // scan workspace
  __shared__ int rpl[NPB];     // exclusive scan of pad8(deg)
  __shared__ int tot;
  int b = blockIdx.x, t = threadIdx.x;
  if (t == 0) tot = 0;
  for (int i = t; i < NPB; i += 256) c[i] = 0;
  __syncthreads();
  // gather this bucket's runs from every scatter block
  for (int k = t; k < ABLK; k += 256) {
    int s0 = coff[k * CW + b];
    int s1 = coff[k * CW + b + 1];
    int len = s1 - s0;
    if (len > 0) {
      int r = atomicAdd(&tot, len);
      const u32* p = binbuf + (size_t)k * EPB + s0;
      for (int j = 0; j < len; j++) ebuf[r + j] = p[j];
    }
  }
  __syncthreads();
  int cnt = tot;
  // node histogram
  for (int i = t; i < cnt; i += 256) {
    u32 p = ebuf[i];
    u32 s = p / (u32)NPB;
    atomicAdd(&c[p - s * (u32)NPB], 1);
  }
  __syncthreads();
  int deg = (t < NPB) ? c[t] : 0;
  int p8 = (deg + 7) & ~7;
  sc[t] = p8;
  __syncthreads();
  for (int o = 1; o < 256; o <<= 1) {
    int add = (t >= o) ? sc[t - o] : 0;
    __syncthreads();
    sc[t] += add;
    __syncthreads();
  }
  int colbase = b * COLCAP;
  if (t < NPB) {
    int rp = sc[t] - p8;
    rpl[t] = rp;
    int node = b * NPB + t;
    rowinfo[node] = make_int2(colbase + rp, p8);
    dis[node] = rsqrtf((float)deg + 1.0f);
    for (int j = deg; j < p8; j++) col[colbase + rp + j] = ZROW;  // pad slots
    c[t] = 0;                                                     // reset as cursor
  }
  __syncthreads();
  // scatter col (bucket-local region, L2-resident)
  for (int i = t; i < cnt; i += 256) {
    u32 p = ebuf[i];
    u32 s = p / (u32)NPB;
    int ld = (int)(p - s * (u32)NPB);
    int pos = atomicAdd(&c[ld], 1);
    col[colbase + rpl[ld] + pos] = (int)s;
  }
  if (b == 0)
    for (int i = t; i < EMB; i += 256) {
      hs1[(size_t)ZROW * EMB + i] = 0;      // zero rows for pad gathers
      y1[(size_t)ZROW * EMB + i] = 0;
    }
}

// ---------------- GEMM1 via MFMA 16x16x32 f16 (W in register B-frags) ----------------

__global__ __launch_bounds__(256) void k_gemm1(const float* __restrict__ x,
                                               const float* __restrict__ W1,
                                               const float* __restrict__ dis,
                                               u16* __restrict__ hs1) {
  int wid = (blockIdx.x * 256 + threadIdx.x) >> 6;   // wave id = 16-row tile
  if (wid >= NTILE) return;
  int l = threadIdx.x & 63;
  int m = l & 15, q = l >> 4;
  f16x8 B[4][2];
#pragma unroll
  for (int s = 0; s < 4; ++s)
#pragma unroll
    for (int h = 0; h < 2; ++h)
#pragma unroll
      for (int j = 0; j < 8; ++j)
        B[s][h][j] = (f16)W1[(s * 32 + q * 8 + j) * EMB + h * 16 + m];
  int row = wid * 16 + m;
  const float* xr = x + (size_t)row * FEAT + q * 8;
  f32x4 acc0 = {0.f, 0.f, 0.f, 0.f}, acc1 = {0.f, 0.f, 0.f, 0.f};
#pragma unroll
  for (int s = 0; s < 4; ++s) {
    f32x4 xa = __builtin_nontemporal_load((const f32x4*)(xr + s * 32));
    f32x4 xb = __builtin_nontemporal_load((const f32x4*)(xr + s * 32 + 4));
    f16x8 A;
    A[0] = (f16)xa.x; A[1] = (f16)xa.y; A[2] = (f16)xa.z; A[3] = (f16)xa.w;
    A[4] = (f16)xb.x; A[5] = (f16)xb.y; A[6] = (f16)xb.z; A[7] = (f16)xb.w;
    acc0 = __builtin_amdgcn_mfma_f32_16x16x32_f16(A, B[s][0], acc0, 0, 0, 0);
    acc1 = __builtin_amdgcn_mfma_f32_16x16x32_f16(A, B[s][1], acc1, 0, 0, 0);
  }
  f32x4 dq = *(const f32x4*)(dis + wid * 16 + q * 4);
  u16* o = hs1 + (size_t)(wid * 16) * EMB;
#pragma unroll
  for (int i = 0; i < 4; ++i) {
    int r = q * 4 + i;
    float dv = (i == 0) ? dq.x : (i == 1) ? dq.y : (i == 2) ? dq.z : dq.w;
    o[(size_t)r * EMB + m]      = __half_as_ushort(__float2half_rn(acc0[i] * dv));
    o[(size_t)r * EMB + 16 + m] = __half_as_ushort(__float2half_rn(acc1[i] * dv));
  }
}

// ---------------- Aggregation: 8 lanes/node, half2-native (R9-proven structural best) ----------------

__device__ __forceinline__ void acch(f32x4& A, uint2 v) {
  float2 f0 = __half22float2(*(__half2*)&v.x);
  float2 f1 = __half22float2(*(__half2*)&v.y);
  f32x4 f = {f0.x, f0.y, f1.x, f1.y};
  A += f;
}

__device__ __forceinline__ float4 agg_node(const u16* __restrict__ hs,
                                           const int2* __restrict__ rowinfo,
                                           const int* __restrict__ col,
                                           int node, int sub) {
  const uint2* t2 = (const uint2*)hs;       // row = 8 chunks of 8B
  int2 ri = rowinfo[node];
  int a0 = ri.x, na = ri.y;                 // pad8 degree; a0 8-slot aligned
  const int* cp = col + a0;
  f32x4 A = {0.f, 0.f, 0.f, 0.f};
  if (na > 0) {
    int4 c0 = *(const int4*)cp;
    int4 c1 = *(const int4*)(cp + 4);
    uint2 v0 = t2[(size_t)c0.x * 8 + sub];
    uint2 v1 = t2[(size_t)c0.y * 8 + sub];
    uint2 v2 = t2[(size_t)c0.z * 8 + sub];
    uint2 v3 = t2[(size_t)c0.w * 8 + sub];
    uint2 v4 = t2[(size_t)c1.x * 8 + sub];
    uint2 v5 = t2[(size_t)c1.y * 8 + sub];
    uint2 v6 = t2[(size_t)c1.z * 8 + sub];
    uint2 v7 = t2[(size_t)c1.w * 8 + sub];
    for (int i = 8; i < na; i += 8) {
      int4 d0 = *(const int4*)(cp + i);
      int4 d1 = *(const int4*)(cp + i + 4);
      uint2 w0 = t2[(size_t)d0.x * 8 + sub];  // next set in flight before consuming
      uint2 w1 = t2[(size_t)d0.y * 8 + sub];
      uint2 w2 = t2[(size_t)d0.z * 8 + sub];
      uint2 w3 = t2[(size_t)d0.w * 8 + sub];
      uint2 w4 = t2[(size_t)d1.x * 8 + sub];
      uint2 w5 = t2[(size_t)d1.y * 8 + sub];
      uint2 w6 = t2[(size_t)d1.z * 8 + sub];
      uint2 w7 = t2[(size_t)d1.w * 8 + sub];
      acch(A, v0); acch(A, v1); acch(A, v2); acch(A, v3);
      acch(A, v4); acch(A, v5); acch(A, v6); acch(A, v7);
      v0 = w0; v1 = w1; v2 = w2; v3 = w3;
      v4 = w4; v5 = w5; v6 = w6; v7 = w7;
    }
    acch(A, v0); acch(A, v1); acch(A, v2); acch(A, v3);
    acch(A, v4); acch(A, v5); acch(A, v6); acch(A, v7);
  }
  // self-loop contribution (row carries the src-side dis factor already)
  acch(A, t2[(size_t)node * 8 + sub]);
  return make_float4(A.x, A.y, A.z, A.w);
}

// grid = AGB blocks; wave handles 8 nodes, lane group (l>>3) one node, sub=l&7
__global__ __launch_bounds__(256) void k_agg1(const u16* __restrict__ hs,
                                              const int2* __restrict__ rowinfo,
                                              const int* __restrict__ col,
                                              const float* __restrict__ dis,
                                              const float* __restrict__ b,
                                              u16* __restrict__ out) {
  int t = threadIdx.x;
  int l = t & 63;
  int node = blockIdx.x * 32 + (t >> 6) * 8 + (l >> 3);
  int sub = l & 7;
  float4 A = agg_node(hs, rowinfo, col, node, sub);
  float d = dis[node];
  float4 bq = ((const float4*)b)[sub];
  float4 o = relu_row(A, d, bq);             // out1 = relu(A*d + b1)
  o.x *= d; o.y *= d; o.z *= d; o.w *= d;    // store y = out1 * dis (layer-2 src prescale)
  ((u16x4*)(out + (size_t)node * EMB))[sub] = f4_to_h4(o);
}

__global__ __launch_bounds__(256) void k_agg2pool(const u16* __restrict__ hs,
                                                  const int2* __restrict__ rowinfo,
                                                  const int* __restrict__ col,
                                                  const float* __restrict__ dis,
                                                  const float* __restrict__ W2,
                                                  const float* __restrict__ b2,
                                                  const float* __restrict__ Wo,
                                                  const int* __restrict__ batch,
                                                  float* __restrict__ gaccP) {
  __shared__ float W2L[32][32];              // W2[k][j], row-major
  int t = threadIdx.x;
  for (int i = t; i < 32 * 32; i += 256) ((float*)W2L)[i] = W2[i];
  __syncthreads();
  int l = t & 63;
  int node = blockIdx.x * 32 + (t >> 6) * 8 + (l >> 3);
  int sub = l & 7;
  float4 A = agg_node(hs, rowinfo, col, node, sub);  // s = Sum(y[src]) + y[node]
  // z[4sub..4sub+3] = (s @ W2)[those cols]; s distributed across the node's 8 lanes
  int base = l & ~7;
  float4 z = make_float4(0.f, 0.f, 0.f, 0.f);
#pragma unroll
  for (int s8 = 0; s8 < 8; ++s8) {
    float sx = __shfl(A.x, base + s8);
    float sy = __shfl(A.y, base + s8);
    float sz = __shfl(A.z, base + s8);
    float sw = __shfl(A.w, base + s8);
    float4 w0 = *(const float4*)&W2L[4 * s8 + 0][sub * 4];
    float4 w1 = *(const float4*)&W2L[4 * s8 + 1][sub * 4];
    float4 w2 = *(const float4*)&W2L[4 * s8 + 2][sub * 4];
    float4 w3 = *(const float4*)&W2L[4 * s8 + 3][sub * 4];
    z.x = fmaf(sx, w0.x, fmaf(sy, w1.x, fmaf(sz, w2.x, fmaf(sw, w3.x, z.x))));
    z.y = fmaf(sx, w0.y, fmaf(sy, w1.y, fmaf(sz, w2.y, fmaf(sw, w3.y, z.y))));
    z.z = fmaf(sx, w0.z, fmaf(sy, w1.z, fmaf(sz, w2.z, fmaf(sw, w3.z, z.z))));
    z.w = fmaf(sx, w0.w, fmaf(sy, w1.w, fmaf(sz, w2.w, fmaf(sw, w3.w, z.w))));
  }
  float d = dis[node];
  float4 bq = ((const float4*)b2)[sub];
  float4 o = relu_row(z, d, bq);             // relu((s@W2)*dis + b2)
  float4 wq = ((const float4*)Wo)[sub];
  float p = o.x * wq.x + o.y * wq.y + o.z * wq.z + o.w * wq.w;
  p += __shfl_xor(p, 1);
  p += __shfl_xor(p, 2);
  p += __shfl_xor(p, 4);
  if (sub == 0)
    atomicAdd(&gaccP[(node & (NCOPY - 1)) * N_GRAPHS + batch[node]], p);
}

// finalize (absorbs k_gcnt: per-graph node count via binary search on sorted batch)
__global__ __launch_bounds__(256) void k_finalize(const float* __restrict__ gaccP,
                                                  const int* __restrict__ batch,
                                                  const float* __restrict__ bo,
                                                  float* __restrict__ out) {
  int g = blockIdx.x * 256 + threadIdx.x;
  if (g < N_GRAPHS) {
    int lo = 0, hi = N_NODES;
    while (lo < hi) { int mid = (lo + hi) >> 1; if (batch[mid] < g) lo = mid + 1; else hi = mid; }
    int lo1 = lo; hi = N_NODES;
    while (lo < hi) { int mid = (lo + hi) >> 1; if (batch[mid] < g + 1) lo = mid + 1; else hi = mid; }
    int cntg = lo - lo1;
    float s = 0.f;
#pragma unroll 8
    for (int c = 0; c < NCOPY; ++c) s += gaccP[c * N_GRAPHS + g];
    out[g] = s / fmaxf((float)cntg, 1.0f) + bo[0];
  }
}

// ---------------- launch ----------------

extern "C" void kernel_launch(void* const* d_in, const int* in_sizes, int n_in,
                              void* d_out, int out_size, void* d_ws, size_t ws_size,
                              hipStream_t stream) {
  const float* x     = (const float*)d_in[0];
  const int*   ei    = (const int*)d_in[1];   // [2, E]: src then dst
  const int*   batch = (const int*)d_in[2];
  const float* W1    = (const float*)d_in[3];
  const float* b1    = (const float*)d_in[4];
  const float* W2    = (const float*)d_in[5];
  const float* b2    = (const float*)d_in[6];
  const float* Wo    = (const float*)d_in[7];
  const float* bo    = (const float*)d_in[8];
  float* out = (float*)d_out;

  const int* src = ei;
  const int* dst = ei + N_EDGES;

  char* w = (char*)d_ws;
  float* gaccP   = (float*)w;  w += (size_t)NCOPY * N_GRAPHS * 4;     // zeroed by k_scat
  int*   coff    = (int*)w;    w += (size_t)ABLK * CW * 4;            // 1.03 MB
  u32*   binbuf  = (u32*)w;    w += (size_t)ABLK * EPB * 4;           // 6.4 MB
  int*   col     = (int*)w;    w += ((size_t)NBKT * COLCAP + 64) * 4; // 10.2 MB
  int2*  rowinfo = (int2*)w;   w += (size_t)(N_NODES + 8) * 8;        // 800 KB
  float* dis     = (float*)w;  w += (size_t)N_NODES * 4;
  u16*   hs1     = (u16*)w;    w += (size_t)(N_NODES + 1) * EMB * 2;  // +1 zero row
  u16*   out1    = (u16*)w;    w += (size_t)(N_NODES + 1) * EMB * 2;  // +1 zero row (y table)

  const int GB = (NTILE * 64 + 255) / 256;  // 1563 MFMA blocks

  k_scat<<<ABLK, 256, 0, stream>>>(src, dst, coff, binbuf, gaccP);
  k_build<<<NBKT, 256, 0, stream>>>(binbuf, coff, col, rowinfo, dis, hs1, out1);
  k_gemm1<<<GB, 256, 0, stream>>>(x, W1, dis, hs1);
  k_agg1<<<AGB, 256, 0, stream>>>(hs1, rowinfo, col, dis, b1, out1);
  k_agg2pool<<<AGB, 256, 0, stream>>>(out1, rowinfo, col, dis, W2, b2, Wo, batch, gaccP);
  k_finalize<<<2, 256, 0, stream>>>(gaccP, batch, bo, out);
}